// Round 15
// baseline (870.905 us; speedup 1.0000x reference)
//
#include <hip/hip_runtime.h>
#include <hip/hip_bf16.h>
#include <math.h>

#define B_ 256
#define L_ 49
#define V_ 10000
#define E_ 512
#define H_ 512
#define K_ 512
#define T_ 15

typedef __bf16 bf16x8 __attribute__((ext_vector_type(8)));
typedef float f32x4 __attribute__((ext_vector_type(4)));

#define AS1 __attribute__((address_space(1)))
#define AS3 __attribute__((address_space(3)))

__device__ __forceinline__ float tanh_fast(float x)
{
    const float ax = fabsf(x);
    const float e = __expf(2.f * ax);
    const float t = 1.f - 2.f / (e + 1.f);
    return copysignf(t, x);
}

// ---------------------------------------------------------------------------
// Merged fp32 -> bf16 casts: 5 used segments (6 slots), n4 % 256 == 0 each.
// ---------------------------------------------------------------------------
struct CvtSegs {
    const float* src[6];
    __hip_bfloat16* dst[6];
    int blk_end[6];
};

__global__ __launch_bounds__(256) void cvt_multi_kernel(CvtSegs s)
{
    const int blk = blockIdx.x;
    int seg = 0;
    while (blk >= s.blk_end[seg]) ++seg;
    const int base = seg ? s.blk_end[seg - 1] : 0;
    const int i = (blk - base) * 256 + threadIdx.x;
    const float4 v = ((const float4*)s.src[seg])[i];
    __hip_bfloat16 o[4];
    o[0] = (__hip_bfloat16)v.x; o[1] = (__hip_bfloat16)v.y;
    o[2] = (__hip_bfloat16)v.z; o[3] = (__hip_bfloat16)v.w;
    *(ushort4*)(s.dst[seg] + (size_t)i * 4) = *(ushort4*)o;
}

// ---------------------------------------------------------------------------
// Transpose + cast: out[c*R + r] = bf16(in[r*C + c]). 32x32 LDS tiles.
// ---------------------------------------------------------------------------
__global__ __launch_bounds__(256) void transpose_cast_kernel(
    const float* __restrict__ in, __hip_bfloat16* __restrict__ out, int R, int Cc)
{
    __shared__ float tile[32][33];
    const int tr0 = blockIdx.y * 32, tc0 = blockIdx.x * 32;
    const int tx = threadIdx.x & 31, ty = threadIdx.x >> 5;
#pragma unroll
    for (int i = 0; i < 32; i += 8)
        tile[ty + i][tx] = in[(size_t)(tr0 + ty + i) * Cc + tc0 + tx];
    __syncthreads();
#pragma unroll
    for (int i = 0; i < 32; i += 8)
        out[(size_t)(tc0 + ty + i) * R + tr0 + tx] = (__hip_bfloat16)tile[tx][ty + i];
}

// ---------------------------------------------------------------------------
// bfull[i] = bih[i] + dot(Wih[i, E:], b0)
// ---------------------------------------------------------------------------
__global__ __launch_bounds__(256) void bfull_kernel(
    const float* __restrict__ Wih, const float* __restrict__ b0,
    const float* __restrict__ bih, float* __restrict__ bfull)
{
    const int i = blockIdx.x * 256 + threadIdx.x;
    if (i >= 3 * H_) return;
    const float* wrow = Wih + (size_t)i * (E_ + H_) + E_;
    float acc = bih[i];
    for (int j = 0; j < H_; ++j) acc += wrow[j] * b0[j];
    bfull[i] = acc;
}

// ---------------------------------------------------------------------------
// Embedding gather + cast: out[t*B+b, :] = bf16(emb[captions[b,t], :])
// ---------------------------------------------------------------------------
__global__ __launch_bounds__(128) void emb_gather_kernel(
    const int* __restrict__ caps, const float* __restrict__ emb,
    __hip_bfloat16* __restrict__ out)
{
    const int r = blockIdx.x;
    const int t = r >> 8;
    const int b = r & 255;
    const int cap = caps[(size_t)b * T_ + t];
    const int e = threadIdx.x * 4;
    const float4 v = *(const float4*)(emb + (size_t)cap * E_ + e);
    __hip_bfloat16 o[4];
    o[0] = (__hip_bfloat16)v.x; o[1] = (__hip_bfloat16)v.y;
    o[2] = (__hip_bfloat16)v.z; o[3] = (__hip_bfloat16)v.w;
    *(ushort4*)(out + (size_t)r * E_ + e) = *(ushort4*)o;
}

// ---------------------------------------------------------------------------
// 128x128-tile bf16 MFMA GEMM (NT), BK=64, XCD-swizzled 1D grid (m204).
// ---------------------------------------------------------------------------
template <typename OutT>
__global__ __launch_bounds__(256) void gemm_bf16_nt128_kernel(
    const __hip_bfloat16* __restrict__ A, const __hip_bfloat16* __restrict__ Bw,
    const float* __restrict__ bias, OutT* __restrict__ C,
    int N, int Kd, int lda, int ldb, int ldc, int nby)
{
    int wg = blockIdx.x;
    {
        const int nwg = gridDim.x;
        const int q = nwg >> 3, r = nwg & 7;
        const int xcd = wg & 7, idx = wg >> 3;
        wg = (xcd < r ? xcd * (q + 1) : r * (q + 1) + (xcd - r) * q) + idx;
    }
    const int by = wg % nby;
    const int bx = wg / nby;
    const int row0 = by * 128;
    const int col0 = bx * 128;

    __shared__ __hip_bfloat16 Asl[128 * 64];
    __shared__ __hip_bfloat16 Bsl[128 * 64];
    const int tid  = threadIdx.x;
    const int lane = tid & 63;
    const int w    = tid >> 6;
    const int wm   = w >> 1, wn = w & 1;

    const int srow = tid >> 3;
    const int scol = (tid & 7) << 3;

    const int lr = lane & 15;
    const int lk = (lane >> 4) << 3;

    f32x4 acc[4][4] = {};

    const __hip_bfloat16* gA = A + (size_t)(row0 + srow) * lda + scol;
    bool bv[4];
    const __hip_bfloat16* gB[4];
#pragma unroll
    for (int i = 0; i < 4; ++i) {
        const int br = col0 + i * 32 + srow;
        bv[i] = br < N;
        gB[i] = Bw + (size_t)br * ldb + scol;
    }

    for (int k0 = 0; k0 < Kd; k0 += 64) {
        __syncthreads();
#pragma unroll
        for (int i = 0; i < 4; ++i)
            __builtin_amdgcn_global_load_lds((const AS1 void*)(gA + (size_t)i * 32 * lda + k0),
                (AS3 void*)(Asl + i * 2048 + tid * 8), 16, 0, 0);
#pragma unroll
        for (int i = 0; i < 4; ++i)
            if (bv[i]) __builtin_amdgcn_global_load_lds((const AS1 void*)(gB[i] + k0),
                (AS3 void*)(Bsl + i * 2048 + tid * 8), 16, 0, 0);
        __syncthreads();

#pragma unroll
        for (int ks = 0; ks < 2; ++ks) {
            bf16x8 af[4], bfr[4];
#pragma unroll
            for (int i = 0; i < 4; ++i)
                af[i] = *(const bf16x8*)(Asl + (wm * 64 + i * 16 + lr) * 64 + ks * 32 + lk);
#pragma unroll
            for (int j = 0; j < 4; ++j)
                bfr[j] = *(const bf16x8*)(Bsl + (wn * 64 + j * 16 + lr) * 64 + ks * 32 + lk);
#pragma unroll
            for (int i = 0; i < 4; ++i)
#pragma unroll
                for (int j = 0; j < 4; ++j)
                    acc[i][j] = __builtin_amdgcn_mfma_f32_16x16x32_bf16(
                        af[i], bfr[j], acc[i][j], 0, 0, 0);
        }
    }

    const int orow = (lane >> 4) << 2;
#pragma unroll
    for (int i = 0; i < 4; ++i) {
#pragma unroll
        for (int j = 0; j < 4; ++j) {
            const int col = col0 + wn * 64 + j * 16 + lr;
            if (col >= N) continue;
            const float bvv = bias ? bias[col] : 0.f;
            const int rowb = row0 + wm * 64 + i * 16 + orow;
#pragma unroll
            for (int r = 0; r < 4; ++r)
                C[(size_t)(rowb + r) * ldc + col] = (OutT)(acc[i][j][r] + bvv);
        }
    }
}

// ---------------------------------------------------------------------------
// 64x64-tile bf16 MFMA GEMM body (NT), BK=64, double-buffered LDS with
// prefetch-before-compute (r10 form). Optional Cin add (CinT = float or bf16).
// ---------------------------------------------------------------------------
template <typename OutT, typename CinT>
__device__ __forceinline__ void gemm_nt_body(
    const __hip_bfloat16* __restrict__ A, const __hip_bfloat16* __restrict__ Bw,
    const float* __restrict__ bias, const CinT* __restrict__ Cin, int ldcin,
    OutT* __restrict__ C, int M, int N, int Kd, int lda, int ldb, int ldc,
    int bx, int by)
{
    __shared__ __hip_bfloat16 Asl[2][64 * 64];
    __shared__ __hip_bfloat16 Bsl[2][64 * 64];
    const int tid  = threadIdx.x;
    const int lane = tid & 63;
    const int w    = tid >> 6;
    const int wm   = w >> 1, wn = w & 1;
    const int row0 = by * 64;
    const int col0 = bx * 64;

    const int srow = tid >> 3;
    const int scol = (tid & 7) << 3;

    const int lr = lane & 15;
    const int lk = (lane >> 4) << 3;

    f32x4 acc[2][2] = {};

    const __hip_bfloat16* gA0 = A + (size_t)(row0 + srow) * lda + scol;
    const __hip_bfloat16* gA1 = gA0 + (size_t)32 * lda;
    const int br0 = col0 + srow, br1 = br0 + 32;
    const __hip_bfloat16* gB0 = Bw + (size_t)br0 * ldb + scol;
    const __hip_bfloat16* gB1 = gB0 + (size_t)32 * ldb;
    const bool v0 = br0 < N, v1 = br1 < N;

    auto stage = [&](int buf, int k0) {
        __builtin_amdgcn_global_load_lds((const AS1 void*)(gA0 + k0),
            (AS3 void*)(&Asl[buf][tid * 8]), 16, 0, 0);
        __builtin_amdgcn_global_load_lds((const AS1 void*)(gA1 + k0),
            (AS3 void*)(&Asl[buf][2048 + tid * 8]), 16, 0, 0);
        if (v0) __builtin_amdgcn_global_load_lds((const AS1 void*)(gB0 + k0),
            (AS3 void*)(&Bsl[buf][tid * 8]), 16, 0, 0);
        if (v1) __builtin_amdgcn_global_load_lds((const AS1 void*)(gB1 + k0),
            (AS3 void*)(&Bsl[buf][2048 + tid * 8]), 16, 0, 0);
    };

    stage(0, 0);
    __syncthreads();
    int cur = 0;
    for (int k0 = 0; k0 < Kd; k0 += 64) {
        if (k0 + 64 < Kd) stage(cur ^ 1, k0 + 64);

#pragma unroll
        for (int ks = 0; ks < 2; ++ks) {
            bf16x8 af[2], bfr[2];
#pragma unroll
            for (int i = 0; i < 2; ++i)
                af[i] = *(const bf16x8*)(&Asl[cur][(wm * 32 + i * 16 + lr) * 64 + ks * 32 + lk]);
#pragma unroll
            for (int j = 0; j < 2; ++j)
                bfr[j] = *(const bf16x8*)(&Bsl[cur][(wn * 32 + j * 16 + lr) * 64 + ks * 32 + lk]);
#pragma unroll
            for (int i = 0; i < 2; ++i)
#pragma unroll
                for (int j = 0; j < 2; ++j)
                    acc[i][j] = __builtin_amdgcn_mfma_f32_16x16x32_bf16(
                        af[i], bfr[j], acc[i][j], 0, 0, 0);
        }
        __syncthreads();
        cur ^= 1;
    }

    const int orow = (lane >> 4) << 2;
#pragma unroll
    for (int i = 0; i < 2; ++i) {
#pragma unroll
        for (int j = 0; j < 2; ++j) {
            const int col = col0 + wn * 32 + j * 16 + lr;
            if (col >= N) continue;
            const float bvv = bias ? bias[col] : 0.f;
            const int rowb = row0 + wm * 32 + i * 16 + orow;
#pragma unroll
            for (int r = 0; r < 4; ++r) {
                float v = acc[i][j][r] + bvv;
                if (Cin) v += (float)Cin[(size_t)(rowb + r) * ldcin + col];
                C[(size_t)(rowb + r) * ldc + col] = (OutT)v;
            }
        }
    }
}

// ---------------------------------------------------------------------------
// Kernel 1: GRU(t-1) + q-projection. One block per b, 512 threads (8 waves).
// Identical math to r14's attn_gru head; q written to global fp32.
// ---------------------------------------------------------------------------
__global__ __launch_bounds__(512) void gru_q_kernel(
    const __hip_bfloat16* __restrict__ gi, const __hip_bfloat16* __restrict__ gh,
    float* __restrict__ h, __hip_bfloat16* __restrict__ hb,
    __hip_bfloat16* __restrict__ h_all, int tprev,
    const __hip_bfloat16* __restrict__ WqT, const float* __restrict__ bq,
    float* __restrict__ q)
{
    const int b = blockIdx.x;
    const int tid = threadIdx.x;       // 0..511
    const int lane = tid & 63;
    const int wave = tid >> 6;         // 0..7
    __shared__ float hb_s[H_];
    __shared__ float q_part[8][H_];

    // ---- GRU(t-1): j = tid covers all H ----
    if (tprev >= 0) {
        const int j = tid;
        const size_t o = (size_t)b * (3 * H_) + j;
        const float ir = (float)gi[o],           hr = (float)gh[o];
        const float iz = (float)gi[o + H_],      hz = (float)gh[o + H_];
        const float in_ = (float)gi[o + 2 * H_], hn = (float)gh[o + 2 * H_];
        const float rr = 1.f / (1.f + expf(-(ir + hr)));
        const float zz = 1.f / (1.f + expf(-(iz + hz)));
        const float nn = tanhf(in_ + rr * hn);
        const size_t hi = (size_t)b * H_ + j;
        const float hnew = (1.f - zz) * nn + zz * h[hi];
        h[hi] = hnew;
        hb_s[j] = hnew;
        const __hip_bfloat16 hv = (__hip_bfloat16)hnew;
        hb[hi] = hv;
        h_all[((size_t)b * T_ + tprev) * H_ + j] = hv;
    } else {
        hb_s[tid] = 0.f;
    }
    __syncthreads();

    // ---- q = h @ Wq^T + bq : 8-wave split-K, lane owns 8 cols ----
    {
        const int j0 = lane * 8;
        float accq[8] = {};
        const __hip_bfloat16* wbase = WqT + (size_t)(wave * 64) * H_ + j0;
#pragma unroll 16
        for (int k = 0; k < 64; ++k) {
            const float hv = hb_s[wave * 64 + k];
            const bf16x8 wv = *(const bf16x8*)(wbase + (size_t)k * H_);
#pragma unroll
            for (int i = 0; i < 8; ++i) accq[i] = fmaf(hv, (float)wv[i], accq[i]);
        }
#pragma unroll
        for (int i = 0; i < 8; ++i) q_part[wave][j0 + i] = accq[i];
    }
    __syncthreads();
    {
        const int j = tid;
        float s = bq[j];
#pragma unroll
        for (int w2 = 0; w2 < 8; ++w2) s += q_part[w2][j];
        q[(size_t)b * H_ + j] = s;
    }
}

// ---------------------------------------------------------------------------
// Kernel 2: attention (blocks 0..255, one per row) PARALLEL WITH gh GEMM
// (blocks 256..351, 64x64 tiles). Both depend only on kernel-1 outputs.
// 256 threads. attn is the r9-proven 4-wave form with q read from global.
// ---------------------------------------------------------------------------
__global__ __launch_bounds__(256) void attn_gh_kernel(
    const float* __restrict__ q, const __hip_bfloat16* __restrict__ kp,
    const __hip_bfloat16* __restrict__ feat, const float* __restrict__ Va,
    const float* __restrict__ bva, __hip_bfloat16* __restrict__ ctx,
    const __hip_bfloat16* __restrict__ hb, const __hip_bfloat16* __restrict__ Whh,
    const float* __restrict__ bhh, __hip_bfloat16* __restrict__ gh)
{
    const int bid = blockIdx.x;
    if (bid >= B_) {
        // ---- gh tile: gh = hb @ Whh^T + bhh (same bx/by map as old gigh) ----
        const int task = bid - B_;         // 0..95
        const int bx = task % 24;
        const int by = task / 24;
        gemm_nt_body<__hip_bfloat16, float>(
            hb, Whh, bhh, (const float*)nullptr, 0, gh,
            B_, 3 * H_, H_, H_, H_, 3 * H_, bx, by);
        return;
    }

    const int b = bid;
    const int tid = threadIdx.x;
    const int lane = tid & 63;
    const int wave = tid >> 6;         // 0..3
    __shared__ float s_sc[64];
    __shared__ float s_w[64];

    float qr[8], va[8];
#pragma unroll
    for (int i = 0; i < 8; ++i) {
        qr[i] = q[(size_t)b * H_ + lane * 8 + i];
        va[i] = Va[lane * 8 + i];
    }

    for (int l = wave; l < L_; l += 4) {
        const bf16x8 kv = *(const bf16x8*)(kp + ((size_t)b * L_ + l) * H_ + lane * 8);
        float s = 0.f;
#pragma unroll
        for (int i = 0; i < 8; ++i) s += tanh_fast(qr[i] + (float)kv[i]) * va[i];
#pragma unroll
        for (int off = 32; off > 0; off >>= 1) s += __shfl_xor(s, off, 64);
        if (lane == 0) s_sc[l] = s + bva[0];
    }
    __syncthreads();

    if (wave == 0) {
        const float v = (lane < L_) ? s_sc[lane] : -1e30f;
        float m = v;
#pragma unroll
        for (int off = 32; off > 0; off >>= 1) m = fmaxf(m, __shfl_xor(m, off, 64));
        const float e = (lane < L_) ? expf(v - m) : 0.f;
        float ssum = e;
#pragma unroll
        for (int off = 32; off > 0; off >>= 1) ssum += __shfl_xor(ssum, off, 64);
        if (lane < L_) s_w[lane] = e / ssum;
    }
    __syncthreads();

    // ctx: two k per thread (pipelined accumulators)
    {
        float acc0 = 0.f, acc1 = 0.f;
        const __hip_bfloat16* fb = feat + (size_t)b * L_ * K_;
#pragma unroll 7
        for (int l = 0; l < L_; ++l) {
            const float wl = s_w[l];
            acc0 = fmaf(wl, (float)fb[(size_t)l * K_ + tid], acc0);
            acc1 = fmaf(wl, (float)fb[(size_t)l * K_ + tid + 256], acc1);
        }
        ctx[(size_t)b * K_ + tid]       = (__hip_bfloat16)acc0;
        ctx[(size_t)b * K_ + tid + 256] = (__hip_bfloat16)acc1;
    }
}

// ---------------------------------------------------------------------------
// Kernel 3: gi = ctx @ Wfused^T + gi_emb_t.  grid (24, 4).
// ---------------------------------------------------------------------------
__global__ __launch_bounds__(256) void gi_kernel(
    const __hip_bfloat16* __restrict__ ctx, const __hip_bfloat16* __restrict__ Wf,
    const __hip_bfloat16* __restrict__ gi_emb_t, __hip_bfloat16* __restrict__ gi)
{
    gemm_nt_body<__hip_bfloat16, __hip_bfloat16>(
        ctx, Wf, nullptr, gi_emb_t, 3 * H_, gi,
        B_, 3 * H_, K_, K_, K_, 3 * H_, blockIdx.x, blockIdx.y);
}

// ---------------------------------------------------------------------------
// Standalone GRU (final step only).
// ---------------------------------------------------------------------------
__global__ __launch_bounds__(256) void gru_kernel(
    const __hip_bfloat16* __restrict__ gi, const __hip_bfloat16* __restrict__ gh,
    float* __restrict__ h, __hip_bfloat16* __restrict__ hb,
    __hip_bfloat16* __restrict__ h_all, int t)
{
    const int idx = blockIdx.x * 256 + threadIdx.x;
    const int b = idx >> 9;
    const int j = idx & (H_ - 1);
    const size_t o = (size_t)b * 3 * H_ + j;
    const float ir = (float)gi[o],           hr = (float)gh[o];
    const float iz = (float)gi[o + H_],      hz = (float)gh[o + H_];
    const float in_ = (float)gi[o + 2 * H_], hn = (float)gh[o + 2 * H_];
    const float r = 1.f / (1.f + expf(-(ir + hr)));
    const float z = 1.f / (1.f + expf(-(iz + hz)));
    const float n = tanhf(in_ + r * hn);
    const float hnew = (1.f - z) * n + z * h[idx];
    h[idx] = hnew;
    const __hip_bfloat16 hv = (__hip_bfloat16)hnew;
    hb[idx] = hv;
    h_all[((size_t)b * T_ + t) * H_ + j] = hv;
}

// ---------------------------------------------------------------------------
extern "C" void kernel_launch(void* const* d_in, const int* in_sizes, int n_in,
                              void* d_out, int out_size, void* d_ws, size_t ws_size,
                              hipStream_t stream)
{
    const float* features = (const float*)d_in[0];
    const int*   captions = (const int*)d_in[1];
    const float* emb  = (const float*)d_in[2];
    const float* Wq   = (const float*)d_in[3];
    const float* bq   = (const float*)d_in[4];
    const float* Uk   = (const float*)d_in[5];
    const float* bk   = (const float*)d_in[6];
    const float* Va   = (const float*)d_in[7];
    const float* bva  = (const float*)d_in[8];
    const float* W0   = (const float*)d_in[9];
    const float* b0   = (const float*)d_in[10];
    const float* Wih  = (const float*)d_in[11];
    const float* bih  = (const float*)d_in[12];
    const float* Whh  = (const float*)d_in[13];
    const float* bhh  = (const float*)d_in[14];
    const float* W1   = (const float*)d_in[15];
    const float* b1   = (const float*)d_in[16];
    float* out = (float*)d_out;

    // fp32 scratch
    float* ws = (float*)d_ws;
    float* h      = ws; ws += B_ * H_;
    float* bfull  = ws; ws += 3 * H_;
    float* qbuf   = ws; ws += B_ * H_;
    // bf16 scratch
    __hip_bfloat16* bws = (__hip_bfloat16*)ws;
    __hip_bfloat16* gi      = bws; bws += (size_t)B_ * 3 * H_;
    __hip_bfloat16* gh      = bws; bws += (size_t)B_ * 3 * H_;
    __hip_bfloat16* gi_emb  = bws; bws += (size_t)T_ * B_ * 3 * H_;
    __hip_bfloat16* feat_bf = bws; bws += (size_t)B_ * L_ * K_;
    __hip_bfloat16* kp_bf   = bws; bws += (size_t)B_ * L_ * H_;
    __hip_bfloat16* W1_bf   = bws; bws += (size_t)V_ * H_;
    __hip_bfloat16* Uk_bf   = bws; bws += (size_t)H_ * K_;
    __hip_bfloat16* WqT_bf  = bws; bws += (size_t)H_ * H_;
    __hip_bfloat16* W0T_bf  = bws; bws += (size_t)K_ * H_;
    __hip_bfloat16* Wih_bf  = bws; bws += (size_t)3 * H_ * (E_ + H_);
    __hip_bfloat16* Whh_bf  = bws; bws += (size_t)3 * H_ * H_;
    __hip_bfloat16* Wfused  = bws; bws += (size_t)3 * H_ * K_;
    __hip_bfloat16* emb_all = bws; bws += (size_t)T_ * B_ * E_;
    __hip_bfloat16* hb      = bws; bws += (size_t)B_ * H_;
    __hip_bfloat16* ctx_bf  = bws; bws += (size_t)B_ * K_;
    __hip_bfloat16* h_all   = bws; bws += (size_t)B_ * T_ * H_;

    hipMemsetAsync(h, 0, (size_t)B_ * H_ * sizeof(float), stream);
    hipMemsetAsync(hb, 0, (size_t)B_ * H_ * sizeof(__hip_bfloat16), stream);

    const dim3 blk(256);

    // ---- prologue: merged casts (5 segments) + transposes ----
    {
        CvtSegs s;
        s.src[0] = features; s.dst[0] = feat_bf;
        s.src[1] = W1;       s.dst[1] = W1_bf;
        s.src[2] = Uk;       s.dst[2] = Uk_bf;
        s.src[3] = Wih;      s.dst[3] = Wih_bf;
        s.src[4] = Whh;      s.dst[4] = Whh_bf;
        const int nb[5] = {
            B_ * L_ * K_ / 1024, V_ * H_ / 1024, H_ * K_ / 1024,
            3 * H_ * (E_ + H_) / 1024, 3 * H_ * H_ / 1024 };
        int cum = 0;
        for (int i = 0; i < 5; ++i) { cum += nb[i]; s.blk_end[i] = cum; }
        s.src[5] = nullptr; s.dst[5] = nullptr; s.blk_end[5] = cum + 1;
        cvt_multi_kernel<<<dim3(cum), blk, 0, stream>>>(s);
    }
    transpose_cast_kernel<<<dim3(H_ / 32, H_ / 32), blk, 0, stream>>>(Wq, WqT_bf, H_, H_);
    transpose_cast_kernel<<<dim3(K_ / 32, H_ / 32), blk, 0, stream>>>(W0, W0T_bf, H_, K_);
    bfull_kernel<<<dim3((3 * H_ + 255) / 256), blk, 0, stream>>>(Wih, b0, bih, bfull);
    emb_gather_kernel<<<dim3(T_ * B_), dim3(128), 0, stream>>>(captions, emb, emb_all);

    // keys_proj = features @ Uk^T + bk -> bf16 [B*L, H]
    gemm_bf16_nt128_kernel<__hip_bfloat16><<<dim3((B_ * L_ / 128) * (H_ / 128)), blk, 0, stream>>>(
        feat_bf, Uk_bf, bk, kp_bf, H_, K_, K_, K_, H_, B_ * L_ / 128);

    // Wfused[3H, K] = Wih[:, E:] @ W0
    gemm_bf16_nt128_kernel<__hip_bfloat16><<<dim3((3 * H_ / 128) * (K_ / 128)), blk, 0, stream>>>(
        Wih_bf + E_, W0T_bf, nullptr, Wfused, K_, H_, E_ + H_, H_, K_, 3 * H_ / 128);

    // gi_emb[t*B+b, :] = emb_t @ WihE^T + (bih + WihE@b0)  -> bf16
    gemm_bf16_nt128_kernel<__hip_bfloat16><<<dim3((T_ * B_ / 128) * (3 * H_ / 128)), blk, 0, stream>>>(
        emb_all, Wih_bf, bfull, gi_emb, 3 * H_, E_, E_, E_ + H_, 3 * H_, T_ * B_ / 128);

    // ---- recurrence: 3 dispatches per step (gh overlapped with attention) ----
    for (int t = 0; t < T_; ++t) {
        gru_q_kernel<<<dim3(B_), dim3(512), 0, stream>>>(
            gi, gh, h, hb, h_all, t - 1, WqT_bf, bq, qbuf);
        attn_gh_kernel<<<dim3(B_ + 96), blk, 0, stream>>>(
            qbuf, kp_bf, feat_bf, Va, bva, ctx_bf,
            hb, Whh_bf, bhh, gh);
        gi_kernel<<<dim3(24, 4), blk, 0, stream>>>(
            ctx_bf, Wfused, gi_emb + (size_t)t * B_ * 3 * H_, gi);
    }
    // final GRU (t = T-1)
    gru_kernel<<<dim3(B_ * H_ / 256), blk, 0, stream>>>(gi, gh, h, hb, h_all, T_ - 1);

    // ---- epilogue: out[b*T+t, :] = h_all @ W1^T + b1 ----
    gemm_bf16_nt128_kernel<float><<<dim3((B_ * T_ / 128) * ((V_ + 127) / 128)), blk, 0, stream>>>(
        h_all, W1_bf, b1, out, V_, H_, H_, H_, V_, B_ * T_ / 128);
}

// Round 16
// 768.865 us; speedup vs baseline: 1.1327x; 1.1327x over previous
//
#include <hip/hip_runtime.h>
#include <hip/hip_bf16.h>
#include <math.h>

#define B_ 256
#define L_ 49
#define V_ 10000
#define E_ 512
#define H_ 512
#define K_ 512
#define T_ 15

typedef __bf16 bf16x8 __attribute__((ext_vector_type(8)));
typedef float f32x4 __attribute__((ext_vector_type(4)));

#define AS1 __attribute__((address_space(1)))
#define AS3 __attribute__((address_space(3)))

__device__ __forceinline__ float tanh_fast(float x)
{
    const float ax = fabsf(x);
    const float e = __expf(2.f * ax);
    const float t = 1.f - 2.f / (e + 1.f);
    return copysignf(t, x);
}

// ---------------------------------------------------------------------------
// Merged fp32 -> bf16 casts: 6 segments, each n4 % 256 == 0 (verified host-side).
// ---------------------------------------------------------------------------
struct CvtSegs {
    const float* src[6];
    __hip_bfloat16* dst[6];
    int blk_end[6];
};

__global__ __launch_bounds__(256) void cvt_multi_kernel(CvtSegs s)
{
    const int blk = blockIdx.x;
    int seg = 0;
    while (blk >= s.blk_end[seg]) ++seg;
    const int base = seg ? s.blk_end[seg - 1] : 0;
    const int i = (blk - base) * 256 + threadIdx.x;
    const float4 v = ((const float4*)s.src[seg])[i];
    __hip_bfloat16 o[4];
    o[0] = (__hip_bfloat16)v.x; o[1] = (__hip_bfloat16)v.y;
    o[2] = (__hip_bfloat16)v.z; o[3] = (__hip_bfloat16)v.w;
    *(ushort4*)(s.dst[seg] + (size_t)i * 4) = *(ushort4*)o;
}

// ---------------------------------------------------------------------------
// Transpose + cast: out[c*R + r] = bf16(in[r*C + c]). 32x32 LDS tiles.
// ---------------------------------------------------------------------------
__global__ __launch_bounds__(256) void transpose_cast_kernel(
    const float* __restrict__ in, __hip_bfloat16* __restrict__ out, int R, int Cc)
{
    __shared__ float tile[32][33];
    const int tr0 = blockIdx.y * 32, tc0 = blockIdx.x * 32;
    const int tx = threadIdx.x & 31, ty = threadIdx.x >> 5;
#pragma unroll
    for (int i = 0; i < 32; i += 8)
        tile[ty + i][tx] = in[(size_t)(tr0 + ty + i) * Cc + tc0 + tx];
    __syncthreads();
#pragma unroll
    for (int i = 0; i < 32; i += 8)
        out[(size_t)(tc0 + ty + i) * R + tr0 + tx] = (__hip_bfloat16)tile[tx][ty + i];
}

// ---------------------------------------------------------------------------
// bfull[i] = bih[i] + dot(Wih[i, E:], b0)
// ---------------------------------------------------------------------------
__global__ __launch_bounds__(256) void bfull_kernel(
    const float* __restrict__ Wih, const float* __restrict__ b0,
    const float* __restrict__ bih, float* __restrict__ bfull)
{
    const int i = blockIdx.x * 256 + threadIdx.x;
    if (i >= 3 * H_) return;
    const float* wrow = Wih + (size_t)i * (E_ + H_) + E_;
    float acc = bih[i];
    for (int j = 0; j < H_; ++j) acc += wrow[j] * b0[j];
    bfull[i] = acc;
}

// ---------------------------------------------------------------------------
// Embedding gather + cast: out[t*B+b, :] = bf16(emb[captions[b,t], :])
// ---------------------------------------------------------------------------
__global__ __launch_bounds__(128) void emb_gather_kernel(
    const int* __restrict__ caps, const float* __restrict__ emb,
    __hip_bfloat16* __restrict__ out)
{
    const int r = blockIdx.x;
    const int t = r >> 8;
    const int b = r & 255;
    const int cap = caps[(size_t)b * T_ + t];
    const int e = threadIdx.x * 4;
    const float4 v = *(const float4*)(emb + (size_t)cap * E_ + e);
    __hip_bfloat16 o[4];
    o[0] = (__hip_bfloat16)v.x; o[1] = (__hip_bfloat16)v.y;
    o[2] = (__hip_bfloat16)v.z; o[3] = (__hip_bfloat16)v.w;
    *(ushort4*)(out + (size_t)r * E_ + e) = *(ushort4*)o;
}

// ---------------------------------------------------------------------------
// 128x128-tile bf16 MFMA GEMM (NT), BK=64, XCD-swizzled 1D grid (m204).
// ---------------------------------------------------------------------------
template <typename OutT>
__global__ __launch_bounds__(256) void gemm_bf16_nt128_kernel(
    const __hip_bfloat16* __restrict__ A, const __hip_bfloat16* __restrict__ Bw,
    const float* __restrict__ bias, OutT* __restrict__ C,
    int N, int Kd, int lda, int ldb, int ldc, int nby)
{
    int wg = blockIdx.x;
    {
        const int nwg = gridDim.x;
        const int q = nwg >> 3, r = nwg & 7;
        const int xcd = wg & 7, idx = wg >> 3;
        wg = (xcd < r ? xcd * (q + 1) : r * (q + 1) + (xcd - r) * q) + idx;
    }
    const int by = wg % nby;
    const int bx = wg / nby;
    const int row0 = by * 128;
    const int col0 = bx * 128;

    __shared__ __hip_bfloat16 Asl[128 * 64];
    __shared__ __hip_bfloat16 Bsl[128 * 64];
    const int tid  = threadIdx.x;
    const int lane = tid & 63;
    const int w    = tid >> 6;
    const int wm   = w >> 1, wn = w & 1;

    const int srow = tid >> 3;
    const int scol = (tid & 7) << 3;

    const int lr = lane & 15;
    const int lk = (lane >> 4) << 3;

    f32x4 acc[4][4] = {};

    const __hip_bfloat16* gA = A + (size_t)(row0 + srow) * lda + scol;
    bool bv[4];
    const __hip_bfloat16* gB[4];
#pragma unroll
    for (int i = 0; i < 4; ++i) {
        const int br = col0 + i * 32 + srow;
        bv[i] = br < N;
        gB[i] = Bw + (size_t)br * ldb + scol;
    }

    for (int k0 = 0; k0 < Kd; k0 += 64) {
        __syncthreads();
#pragma unroll
        for (int i = 0; i < 4; ++i)
            __builtin_amdgcn_global_load_lds((const AS1 void*)(gA + (size_t)i * 32 * lda + k0),
                (AS3 void*)(Asl + i * 2048 + tid * 8), 16, 0, 0);
#pragma unroll
        for (int i = 0; i < 4; ++i)
            if (bv[i]) __builtin_amdgcn_global_load_lds((const AS1 void*)(gB[i] + k0),
                (AS3 void*)(Bsl + i * 2048 + tid * 8), 16, 0, 0);
        __syncthreads();

#pragma unroll
        for (int ks = 0; ks < 2; ++ks) {
            bf16x8 af[4], bfr[4];
#pragma unroll
            for (int i = 0; i < 4; ++i)
                af[i] = *(const bf16x8*)(Asl + (wm * 64 + i * 16 + lr) * 64 + ks * 32 + lk);
#pragma unroll
            for (int j = 0; j < 4; ++j)
                bfr[j] = *(const bf16x8*)(Bsl + (wn * 64 + j * 16 + lr) * 64 + ks * 32 + lk);
#pragma unroll
            for (int i = 0; i < 4; ++i)
#pragma unroll
                for (int j = 0; j < 4; ++j)
                    acc[i][j] = __builtin_amdgcn_mfma_f32_16x16x32_bf16(
                        af[i], bfr[j], acc[i][j], 0, 0, 0);
        }
    }

    const int orow = (lane >> 4) << 2;
#pragma unroll
    for (int i = 0; i < 4; ++i) {
#pragma unroll
        for (int j = 0; j < 4; ++j) {
            const int col = col0 + wn * 64 + j * 16 + lr;
            if (col >= N) continue;
            const float bvv = bias ? bias[col] : 0.f;
            const int rowb = row0 + wm * 64 + i * 16 + orow;
#pragma unroll
            for (int r = 0; r < 4; ++r)
                C[(size_t)(rowb + r) * ldc + col] = (OutT)(acc[i][j][r] + bvv);
        }
    }
}

// ---------------------------------------------------------------------------
// 64x64-tile bf16 MFMA GEMM body (NT), BK=64, double-buffered LDS with
// prefetch-before-compute (r10 form). Optional Cin add (CinT = float or bf16).
// ---------------------------------------------------------------------------
template <typename OutT, typename CinT>
__device__ __forceinline__ void gemm_nt_body(
    const __hip_bfloat16* __restrict__ A, const __hip_bfloat16* __restrict__ Bw,
    const float* __restrict__ bias, const CinT* __restrict__ Cin, int ldcin,
    OutT* __restrict__ C, int M, int N, int Kd, int lda, int ldb, int ldc,
    int bx, int by)
{
    __shared__ __hip_bfloat16 Asl[2][64 * 64];
    __shared__ __hip_bfloat16 Bsl[2][64 * 64];
    const int tid  = threadIdx.x;
    const int lane = tid & 63;
    const int w    = tid >> 6;
    const int wm   = w >> 1, wn = w & 1;
    const int row0 = by * 64;
    const int col0 = bx * 64;

    const int srow = tid >> 3;
    const int scol = (tid & 7) << 3;

    const int lr = lane & 15;
    const int lk = (lane >> 4) << 3;

    f32x4 acc[2][2] = {};

    const __hip_bfloat16* gA0 = A + (size_t)(row0 + srow) * lda + scol;
    const __hip_bfloat16* gA1 = gA0 + (size_t)32 * lda;
    const int br0 = col0 + srow, br1 = br0 + 32;
    const __hip_bfloat16* gB0 = Bw + (size_t)br0 * ldb + scol;
    const __hip_bfloat16* gB1 = gB0 + (size_t)32 * ldb;
    const bool v0 = br0 < N, v1 = br1 < N;

    auto stage = [&](int buf, int k0) {
        __builtin_amdgcn_global_load_lds((const AS1 void*)(gA0 + k0),
            (AS3 void*)(&Asl[buf][tid * 8]), 16, 0, 0);
        __builtin_amdgcn_global_load_lds((const AS1 void*)(gA1 + k0),
            (AS3 void*)(&Asl[buf][2048 + tid * 8]), 16, 0, 0);
        if (v0) __builtin_amdgcn_global_load_lds((const AS1 void*)(gB0 + k0),
            (AS3 void*)(&Bsl[buf][tid * 8]), 16, 0, 0);
        if (v1) __builtin_amdgcn_global_load_lds((const AS1 void*)(gB1 + k0),
            (AS3 void*)(&Bsl[buf][2048 + tid * 8]), 16, 0, 0);
    };

    stage(0, 0);
    __syncthreads();
    int cur = 0;
    for (int k0 = 0; k0 < Kd; k0 += 64) {
        if (k0 + 64 < Kd) stage(cur ^ 1, k0 + 64);

#pragma unroll
        for (int ks = 0; ks < 2; ++ks) {
            bf16x8 af[2], bfr[2];
#pragma unroll
            for (int i = 0; i < 2; ++i)
                af[i] = *(const bf16x8*)(&Asl[cur][(wm * 32 + i * 16 + lr) * 64 + ks * 32 + lk]);
#pragma unroll
            for (int j = 0; j < 2; ++j)
                bfr[j] = *(const bf16x8*)(&Bsl[cur][(wn * 32 + j * 16 + lr) * 64 + ks * 32 + lk]);
#pragma unroll
            for (int i = 0; i < 2; ++i)
#pragma unroll
                for (int j = 0; j < 2; ++j)
                    acc[i][j] = __builtin_amdgcn_mfma_f32_16x16x32_bf16(
                        af[i], bfr[j], acc[i][j], 0, 0, 0);
        }
        __syncthreads();
        cur ^= 1;
    }

    const int orow = (lane >> 4) << 2;
#pragma unroll
    for (int i = 0; i < 2; ++i) {
#pragma unroll
        for (int j = 0; j < 2; ++j) {
            const int col = col0 + wn * 32 + j * 16 + lr;
            if (col >= N) continue;
            const float bvv = bias ? bias[col] : 0.f;
            const int rowb = row0 + wm * 32 + i * 16 + orow;
#pragma unroll
            for (int r = 0; r < 4; ++r) {
                float v = acc[i][j][r] + bvv;
                if (Cin) v += (float)Cin[(size_t)(rowb + r) * ldcin + col];
                C[(size_t)(rowb + r) * ldc + col] = (OutT)v;
            }
        }
    }
}

// ---------------------------------------------------------------------------
// Fused gi+gh (bf16 outputs): z==0: gi = ctx @ Wfused^T + gi_emb_t ;
// z==1: gh = hb @ Whh^T + bhh.  grid (24, 4, 2) = 192 blocks.
// ---------------------------------------------------------------------------
__global__ __launch_bounds__(256) void gemm_gigh_kernel(
    const __hip_bfloat16* __restrict__ ctx, const __hip_bfloat16* __restrict__ Wf,
    const __hip_bfloat16* __restrict__ gi_emb_t,
    const __hip_bfloat16* __restrict__ hb, const __hip_bfloat16* __restrict__ Whh,
    const float* __restrict__ bhh,
    __hip_bfloat16* __restrict__ gi, __hip_bfloat16* __restrict__ gh)
{
    if (blockIdx.z == 0)
        gemm_nt_body<__hip_bfloat16, __hip_bfloat16>(
            ctx, Wf, nullptr, gi_emb_t, 3 * H_, gi,
            B_, 3 * H_, K_, K_, K_, 3 * H_, blockIdx.x, blockIdx.y);
    else
        gemm_nt_body<__hip_bfloat16, float>(
            hb, Whh, bhh, (const float*)nullptr, 0, gh,
            B_, 3 * H_, H_, H_, H_, 3 * H_, blockIdx.x, blockIdx.y);
}

// ---------------------------------------------------------------------------
// Fused [GRU(t-1)] + q-projection + additive attention. One block per b,
// 512 threads (8 waves). r10-exact structure; gi/gh bf16.
// ---------------------------------------------------------------------------
__global__ __launch_bounds__(512) void attn_gru_kernel(
    const __hip_bfloat16* __restrict__ gi, const __hip_bfloat16* __restrict__ gh,
    float* __restrict__ h, __hip_bfloat16* __restrict__ hb,
    __hip_bfloat16* __restrict__ h_all, int tprev,
    const __hip_bfloat16* __restrict__ WqT, const float* __restrict__ bq,
    const __hip_bfloat16* __restrict__ kp, const __hip_bfloat16* __restrict__ feat,
    const float* __restrict__ Va, const float* __restrict__ bva,
    __hip_bfloat16* __restrict__ ctx)
{
    const int b = blockIdx.x;
    const int tid = threadIdx.x;       // 0..511
    const int lane = tid & 63;
    const int wave = tid >> 6;         // 0..7
    __shared__ float hb_s[H_];
    __shared__ float q_part[8][H_];
    __shared__ float q_s[H_];
    __shared__ float s_sc[64];
    __shared__ float s_w[64];

    // ---- GRU(t-1): j = tid covers all H ----
    if (tprev >= 0) {
        const int j = tid;
        const size_t o = (size_t)b * (3 * H_) + j;
        const float ir = (float)gi[o],           hr = (float)gh[o];
        const float iz = (float)gi[o + H_],      hz = (float)gh[o + H_];
        const float in_ = (float)gi[o + 2 * H_], hn = (float)gh[o + 2 * H_];
        const float rr = 1.f / (1.f + expf(-(ir + hr)));
        const float zz = 1.f / (1.f + expf(-(iz + hz)));
        const float nn = tanhf(in_ + rr * hn);
        const size_t hi = (size_t)b * H_ + j;
        const float hnew = (1.f - zz) * nn + zz * h[hi];
        h[hi] = hnew;
        hb_s[j] = hnew;
        const __hip_bfloat16 hv = (__hip_bfloat16)hnew;
        hb[hi] = hv;
        h_all[((size_t)b * T_ + tprev) * H_ + j] = hv;
    } else {
        hb_s[tid] = 0.f;
    }
    __syncthreads();

    // ---- q = h @ Wq^T + bq : 8-wave split-K, lane owns 8 cols ----
    {
        const int j0 = lane * 8;
        float accq[8] = {};
        const __hip_bfloat16* wbase = WqT + (size_t)(wave * 64) * H_ + j0;
#pragma unroll 16
        for (int k = 0; k < 64; ++k) {
            const float hv = hb_s[wave * 64 + k];
            const bf16x8 wv = *(const bf16x8*)(wbase + (size_t)k * H_);
#pragma unroll
            for (int i = 0; i < 8; ++i) accq[i] = fmaf(hv, (float)wv[i], accq[i]);
        }
#pragma unroll
        for (int i = 0; i < 8; ++i) q_part[wave][j0 + i] = accq[i];
    }
    __syncthreads();
    {
        const int j = tid;
        float s = bq[j];
#pragma unroll
        for (int w2 = 0; w2 < 8; ++w2) s += q_part[w2][j];
        q_s[j] = s;
    }
    __syncthreads();

    // ---- scores + softmax ----
    float qr[8], va[8];
#pragma unroll
    for (int i = 0; i < 8; ++i) {
        qr[i] = q_s[lane * 8 + i];
        va[i] = Va[lane * 8 + i];
    }

    for (int l = wave; l < L_; l += 8) {
        const bf16x8 kv = *(const bf16x8*)(kp + ((size_t)b * L_ + l) * H_ + lane * 8);
        float s = 0.f;
#pragma unroll
        for (int i = 0; i < 8; ++i) s += tanh_fast(qr[i] + (float)kv[i]) * va[i];
#pragma unroll
        for (int off = 32; off > 0; off >>= 1) s += __shfl_xor(s, off, 64);
        if (lane == 0) s_sc[l] = s + bva[0];
    }
    __syncthreads();

    if (wave == 0) {
        const float v = (lane < L_) ? s_sc[lane] : -1e30f;
        float m = v;
#pragma unroll
        for (int off = 32; off > 0; off >>= 1) m = fmaxf(m, __shfl_xor(m, off, 64));
        const float e = (lane < L_) ? expf(v - m) : 0.f;
        float ssum = e;
#pragma unroll
        for (int off = 32; off > 0; off >>= 1) ssum += __shfl_xor(ssum, off, 64);
        if (lane < L_) s_w[lane] = e / ssum;
    }
    __syncthreads();

    // ---- ctx: one k per thread ----
    {
        float acc0 = 0.f;
        const __hip_bfloat16* fb = feat + (size_t)b * L_ * K_ + tid;
#pragma unroll 7
        for (int l = 0; l < L_; ++l)
            acc0 = fmaf(s_w[l], (float)fb[(size_t)l * K_], acc0);
        ctx[(size_t)b * K_ + tid] = (__hip_bfloat16)acc0;
    }
}

// ---------------------------------------------------------------------------
// Standalone GRU (final step only).
// ---------------------------------------------------------------------------
__global__ __launch_bounds__(256) void gru_kernel(
    const __hip_bfloat16* __restrict__ gi, const __hip_bfloat16* __restrict__ gh,
    float* __restrict__ h, __hip_bfloat16* __restrict__ hb,
    __hip_bfloat16* __restrict__ h_all, int t)
{
    const int idx = blockIdx.x * 256 + threadIdx.x;
    const int b = idx >> 9;
    const int j = idx & (H_ - 1);
    const size_t o = (size_t)b * 3 * H_ + j;
    const float ir = (float)gi[o],           hr = (float)gh[o];
    const float iz = (float)gi[o + H_],      hz = (float)gh[o + H_];
    const float in_ = (float)gi[o + 2 * H_], hn = (float)gh[o + 2 * H_];
    const float r = 1.f / (1.f + expf(-(ir + hr)));
    const float z = 1.f / (1.f + expf(-(iz + hz)));
    const float n = tanhf(in_ + r * hn);
    const float hnew = (1.f - z) * n + z * h[idx];
    h[idx] = hnew;
    const __hip_bfloat16 hv = (__hip_bfloat16)hnew;
    hb[idx] = hv;
    h_all[((size_t)b * T_ + t) * H_ + j] = hv;
}

// ---------------------------------------------------------------------------
extern "C" void kernel_launch(void* const* d_in, const int* in_sizes, int n_in,
                              void* d_out, int out_size, void* d_ws, size_t ws_size,
                              hipStream_t stream)
{
    const float* features = (const float*)d_in[0];
    const int*   captions = (const int*)d_in[1];
    const float* emb  = (const float*)d_in[2];
    const float* Wq   = (const float*)d_in[3];
    const float* bq   = (const float*)d_in[4];
    const float* Uk   = (const float*)d_in[5];
    const float* bk   = (const float*)d_in[6];
    const float* Va   = (const float*)d_in[7];
    const float* bva  = (const float*)d_in[8];
    const float* W0   = (const float*)d_in[9];
    const float* b0   = (const float*)d_in[10];
    const float* Wih  = (const float*)d_in[11];
    const float* bih  = (const float*)d_in[12];
    const float* Whh  = (const float*)d_in[13];
    const float* bhh  = (const float*)d_in[14];
    const float* W1   = (const float*)d_in[15];
    const float* b1   = (const float*)d_in[16];
    float* out = (float*)d_out;

    // fp32 scratch
    float* ws = (float*)d_ws;
    float* h      = ws; ws += B_ * H_;
    float* bfull  = ws; ws += 3 * H_;
    // bf16 scratch
    __hip_bfloat16* bws = (__hip_bfloat16*)ws;
    __hip_bfloat16* gi      = bws; bws += (size_t)B_ * 3 * H_;
    __hip_bfloat16* gh      = bws; bws += (size_t)B_ * 3 * H_;
    __hip_bfloat16* gi_emb  = bws; bws += (size_t)T_ * B_ * 3 * H_;
    __hip_bfloat16* feat_bf = bws; bws += (size_t)B_ * L_ * K_;
    __hip_bfloat16* kp_bf   = bws; bws += (size_t)B_ * L_ * H_;
    __hip_bfloat16* W1_bf   = bws; bws += (size_t)V_ * H_;
    __hip_bfloat16* Uk_bf   = bws; bws += (size_t)H_ * K_;
    __hip_bfloat16* WqT_bf  = bws; bws += (size_t)H_ * H_;
    __hip_bfloat16* W0T_bf  = bws; bws += (size_t)K_ * H_;
    __hip_bfloat16* Wih_bf  = bws; bws += (size_t)3 * H_ * (E_ + H_);
    __hip_bfloat16* Whh_bf  = bws; bws += (size_t)3 * H_ * H_;
    __hip_bfloat16* Wfused  = bws; bws += (size_t)3 * H_ * K_;
    __hip_bfloat16* emb_all = bws; bws += (size_t)T_ * B_ * E_;
    __hip_bfloat16* hb      = bws; bws += (size_t)B_ * H_;
    __hip_bfloat16* ctx_bf  = bws; bws += (size_t)B_ * K_;
    __hip_bfloat16* h_all   = bws; bws += (size_t)B_ * T_ * H_;

    hipMemsetAsync(h, 0, (size_t)B_ * H_ * sizeof(float), stream);
    hipMemsetAsync(hb, 0, (size_t)B_ * H_ * sizeof(__hip_bfloat16), stream);

    const dim3 blk(256);

    // ---- prologue: merged casts (5 segments) + transposes ----
    {
        CvtSegs s;
        s.src[0] = features; s.dst[0] = feat_bf;
        s.src[1] = W1;       s.dst[1] = W1_bf;
        s.src[2] = Uk;       s.dst[2] = Uk_bf;
        s.src[3] = Wih;      s.dst[3] = Wih_bf;
        s.src[4] = Whh;      s.dst[4] = Whh_bf;
        const int nb[5] = {
            B_ * L_ * K_ / 1024, V_ * H_ / 1024, H_ * K_ / 1024,
            3 * H_ * (E_ + H_) / 1024, 3 * H_ * H_ / 1024 };
        int cum = 0;
        for (int i = 0; i < 5; ++i) { cum += nb[i]; s.blk_end[i] = cum; }
        s.src[5] = nullptr; s.dst[5] = nullptr; s.blk_end[5] = cum + 1;
        cvt_multi_kernel<<<dim3(cum), blk, 0, stream>>>(s);
    }
    transpose_cast_kernel<<<dim3(H_ / 32, H_ / 32), blk, 0, stream>>>(Wq, WqT_bf, H_, H_);
    transpose_cast_kernel<<<dim3(K_ / 32, H_ / 32), blk, 0, stream>>>(W0, W0T_bf, H_, K_);
    bfull_kernel<<<dim3((3 * H_ + 255) / 256), blk, 0, stream>>>(Wih, b0, bih, bfull);
    emb_gather_kernel<<<dim3(T_ * B_), dim3(128), 0, stream>>>(captions, emb, emb_all);

    // keys_proj = features @ Uk^T + bk -> bf16 [B*L, H]
    gemm_bf16_nt128_kernel<__hip_bfloat16><<<dim3((B_ * L_ / 128) * (H_ / 128)), blk, 0, stream>>>(
        feat_bf, Uk_bf, bk, kp_bf, H_, K_, K_, K_, H_, B_ * L_ / 128);

    // Wfused[3H, K] = Wih[:, E:] @ W0
    gemm_bf16_nt128_kernel<__hip_bfloat16><<<dim3((3 * H_ / 128) * (K_ / 128)), blk, 0, stream>>>(
        Wih_bf + E_, W0T_bf, nullptr, Wfused, K_, H_, E_ + H_, H_, K_, 3 * H_ / 128);

    // gi_emb[t*B+b, :] = emb_t @ WihE^T + (bih + WihE@b0)  -> bf16
    gemm_bf16_nt128_kernel<__hip_bfloat16><<<dim3((T_ * B_ / 128) * (3 * H_ / 128)), blk, 0, stream>>>(
        emb_all, Wih_bf, bfull, gi_emb, 3 * H_, E_, E_, E_ + H_, 3 * H_, T_ * B_ / 128);

    // ---- recurrence: 2 dispatches per step ----
    for (int t = 0; t < T_; ++t) {
        attn_gru_kernel<<<dim3(B_), dim3(512), 0, stream>>>(
            gi, gh, h, hb, h_all, t - 1,
            WqT_bf, bq, kp_bf, feat_bf, Va, bva, ctx_bf);
        gemm_gigh_kernel<<<dim3(3 * H_ / 64, B_ / 64, 2), blk, 0, stream>>>(
            ctx_bf, Wfused, gi_emb + (size_t)t * B_ * 3 * H_,
            hb, Whh_bf, bhh, gi, gh);
    }
    // final GRU (t = T-1)
    gru_kernel<<<dim3(B_ * H_ / 256), blk, 0, stream>>>(gi, gh, h, hb, h_all, T_ - 1);

    // ---- epilogue: out[b*T+t, :] = h_all @ W1^T + b1 ----
    gemm_bf16_nt128_kernel<float><<<dim3((B_ * T_ / 128) * ((V_ + 127) / 128)), blk, 0, stream>>>(
        h_all, W1_bf, b1, out, V_, H_, H_, H_, V_, B_ * T_ / 128);
}